// Round 3
// baseline (146.435 us; speedup 1.0000x reference)
//
#include <hip/hip_runtime.h>
#include <hip/hip_bf16.h>

typedef __attribute__((ext_vector_type(4))) float f32x4;
typedef __attribute__((ext_vector_type(8))) short bf16x8;

static constexpr int B   = 2;
static constexpr int N   = 2048;
static constexpr int F   = 64;
static constexpr int H   = 4;
static constexpr int HID = 128;
static constexpr int BN  = B * N;
static constexpr size_t LOG_SZ = (size_t)B * N * N * 3;

__device__ __forceinline__ float sigmoidf_(float x) { return 1.0f / (1.0f + __expf(-x)); }
__device__ __forceinline__ float tanhf_(float x) {
  float e = __expf(2.0f * x);
  return 1.0f - 2.0f / (e + 1.0f);      // inf-safe: e=inf -> 1, e=0 -> -1
}
// RNE bf16 split: v = hi + lo with ~2^-17 relative error
__device__ __forceinline__ void split_bf16(float v, short& hi, short& lo) {
  unsigned u = __float_as_uint(v);
  unsigned hr = (u + 0x7FFFu + ((u >> 16) & 1u)) >> 16;
  hi = (short)hr;
  float hv = __uint_as_float(hr << 16);
  float res = v - hv;
  unsigned u2 = __float_as_uint(res);
  lo = (short)((u2 + 0x7FFFu + ((u2 >> 16) & 1u)) >> 16);
}

// ------------- K0: transpose + bf16x2-split all 12 weight matrices -------------
struct PrepArgs {
  const float* src[12];
  short* hi[12];
  short* lo[12];
  int K[12];                 // rows of src (256 for W, 128 for R); cols always 128
};
__global__ __launch_bounds__(256) void k_prep_w(PrepArgs pa) {
  const int m  = blockIdx.y;
  const int K  = pa.K[m];
  const int kt = blockIdx.x >> 2;      // k-tile (32 rows of src)
  const int ct = blockIdx.x & 3;       // col-tile (32 cols of src)
  if (kt * 32 >= K) return;
  const int t  = threadIdx.x;
  const int tx = t & 31, ty = t >> 5;  // ty 0..7
  __shared__ float tl[32][33];
  const float* src = pa.src[m];
  #pragma unroll
  for (int p = 0; p < 4; ++p) {
    const int r = ty + p * 8;
    tl[r][tx] = src[(size_t)(kt * 32 + r) * HID + ct * 32 + tx];
  }
  __syncthreads();
  short* ph = pa.hi[m];
  short* pl = pa.lo[m];
  #pragma unroll
  for (int p = 0; p < 4; ++p) {
    const int cl = ty + p * 8;                     // local col of W = row of Wt
    float v = tl[tx][cl];
    short hi, lo; split_bf16(v, hi, lo);
    const size_t o = (size_t)(ct * 32 + cl) * K + kt * 32 + tx;
    ph[o] = hi; pl[o] = lo;
  }
}

// ------------- K1: hfeat = x @ gat_kernel ; s_self, s_neigh ; h -> bf16x2 -------------
__global__ __launch_bounds__(128) void k_feat(
    const float* __restrict__ x, const float* __restrict__ gk,
    const float* __restrict__ asel, const float* __restrict__ anei,
    float* __restrict__ hfeat, float* __restrict__ sself, float* __restrict__ sneigh,
    const float* __restrict__ h0, const float* __restrict__ h1, const float* __restrict__ h2,
    short* __restrict__ hh0, short* __restrict__ hl0,
    short* __restrict__ hh1, short* __restrict__ hl1,
    short* __restrict__ hh2, short* __restrict__ hl2) {
  const int bn = blockIdx.x;
  const int t  = threadIdx.x;
  __shared__ float xs[F];
  if (t < F) xs[t] = x[(size_t)bn * F + t];
  const size_t o = (size_t)bn * HID + t;
  { short hi, lo; split_bf16(h0[o], hi, lo); hh0[o] = hi; hl0[o] = lo; }
  { short hi, lo; split_bf16(h1[o], hi, lo); hh1[o] = hi; hl1[o] = lo; }
  { short hi, lo; split_bf16(h2[o], hi, lo); hh2[o] = hi; hl2[o] = lo; }
  __syncthreads();
  float acc = 0.f;
  #pragma unroll 8
  for (int f = 0; f < F; ++f) acc += xs[f] * gk[f * HID + t];
  hfeat[o] = acc;
  float ps = acc * asel[t];
  float pn = acc * anei[t];
  #pragma unroll
  for (int d = 16; d >= 1; d >>= 1) {
    ps += __shfl_xor(ps, d, 32);
    pn += __shfl_xor(pn, d, 32);
  }
  if ((t & 31) == 0) {
    sself [bn * H + (t >> 5)] = ps;
    sneigh[bn * H + (t >> 5)] = pn;
  }
}

// ------------- K2: sparse GAT attention — one wave per row; conv out as bf16x2 -------------
__global__ __launch_bounds__(256) void k_attn(
    const float* __restrict__ a, const float* __restrict__ hfeat,
    const float* __restrict__ sself, const float* __restrict__ sneigh,
    const float* __restrict__ bias,
    short* __restrict__ conv_hi, short* __restrict__ conv_lo) {
  const int wv   = threadIdx.x >> 6;
  const int lane = threadIdx.x & 63;
  const int bi   = blockIdx.x * 4 + wv;
  const int bbase = bi & ~(N - 1);
  __shared__ int   nbr[4][256];
  __shared__ float wts[4][256][4];
  int*   nb       = nbr[wv];
  float (*wt)[4]  = wts[wv];

  const float si0 = sself[bi * H + 0];
  const float si1 = sself[bi * H + 1];
  const float si2 = sself[bi * H + 2];
  const float si3 = sself[bi * H + 3];
  float den0 = 0.f, den1 = 0.f, den2 = 0.f, den3 = 0.f;
  float acc0 = 0.f, acc1 = 0.f;
  const unsigned long long lmlt = ((unsigned long long)1 << lane) - 1ull;
  const float* arow = a + (size_t)bi * N;
  const float* hb   = hfeat + (size_t)bbase * HID;
  const float* snb  = sneigh + (size_t)bbase * H;
  const int h0 = lane >> 5;
  int num = 0;

  auto flush = [&]() {
    asm volatile("s_waitcnt lgkmcnt(0)" ::: "memory");
    for (int n = lane; n < num; n += 64) {
      const int j = nb[n];
      f32x4 sn = *(const f32x4*)&snb[(size_t)j * H];
      float s0 = si0 + sn[0]; s0 = (s0 > 0.f) ? s0 : 0.2f * s0;
      float s1 = si1 + sn[1]; s1 = (s1 > 0.f) ? s1 : 0.2f * s1;
      float s2 = si2 + sn[2]; s2 = (s2 > 0.f) ? s2 : 0.2f * s2;
      float s3 = si3 + sn[3]; s3 = (s3 > 0.f) ? s3 : 0.2f * s3;
      float w0 = __expf(s0), w1 = __expf(s1), w2 = __expf(s2), w3 = __expf(s3);
      wt[n][0] = w0; wt[n][1] = w1; wt[n][2] = w2; wt[n][3] = w3;
      den0 += w0; den1 += w1; den2 += w2; den3 += w3;
    }
    asm volatile("s_waitcnt lgkmcnt(0)" ::: "memory");
    #pragma unroll 4
    for (int n = 0; n < num; ++n) {
      const int j  = nb[n];
      const float wA = wt[n][h0];
      const float wB = wt[n][h0 + 2];
      const float* hr = hb + (size_t)j * HID;
      acc0 += wA * hr[lane];
      acc1 += wB * hr[lane + 64];
    }
    asm volatile("s_waitcnt lgkmcnt(0)" ::: "memory");
    num = 0;
  };

  for (int jb = 0; jb < N; jb += 256) {
    f32x4 av = *(const f32x4*)&arow[jb + lane * 4];
    #pragma unroll
    for (int e = 0; e < 4; ++e) {
      const unsigned long long m = __ballot(av[e] > 0.5f);
      if (av[e] > 0.5f) {
        const int pos = num + __popcll(m & lmlt);
        nb[pos] = jb + lane * 4 + e;
      }
      num += __popcll(m);
      if (num > 192) flush();
    }
  }
  if (num > 0) flush();

  #pragma unroll
  for (int d = 32; d >= 1; d >>= 1) {
    den0 += __shfl_xor(den0, d, 64);
    den1 += __shfl_xor(den1, d, 64);
    den2 += __shfl_xor(den2, d, 64);
    den3 += __shfl_xor(den3, d, 64);
  }
  const float dA = h0 ? den1 : den0;
  const float dB = h0 ? den3 : den2;
  const float v0 = acc0 / dA + bias[lane];
  const float v1 = acc1 / dB + bias[64 + lane];
  { short hi, lo; split_bf16(v0, hi, lo);
    conv_hi[(size_t)bi * HID + lane] = hi; conv_lo[(size_t)bi * HID + lane] = lo; }
  { short hi, lo; split_bf16(v1, hi, lo);
    conv_hi[(size_t)bi * HID + 64 + lane] = hi; conv_lo[(size_t)bi * HID + 64 + lane] = lo; }
}

// ------------- K3: fused GRU (u,r,c,h') + g = h' @ R, bf16x2 split MFMA -------------
struct GruArgs {
  const short* chi; const short* clo;
  const float* h[3];
  const short* hhi[3]; const short* hlo[3];
  const float* bu[3]; const float* br[3]; const float* bc[3];
  const short* WuH[3]; const short* WuL[3];
  const short* WrH[3]; const short* WrL[3];
  const short* WcH[3]; const short* WcL[3];
  const short* RtH[3]; const short* RtL[3];
  float* hout[3]; __hip_bfloat16* hb[3]; __hip_bfloat16* gb[3];
};

__global__ __launch_bounds__(512, 1) void k_gru(GruArgs ga) {
  const int cell = blockIdx.y;
  const int r0 = blockIdx.x * 64;
  const int t = threadIdx.x;
  const int w = t >> 6, l = t & 63;
  const int grp = w >> 1, ch = w & 1;       // row-group 0..3, col-half 0..1
  const int R0 = r0 + grp * 16;
  const int lr = l & 15, lg = l >> 4;
  const int kb = lg * 8;
  __shared__ float lds[4][16][132];
  float (*my)[132] = lds[grp];

  const short* chi = ga.chi; const short* clo = ga.clo;
  const short* hhi = ga.hhi[cell]; const short* hlo = ga.hlo[cell];
  const float* hsrc = ga.h[cell];
  const float* bu = ga.bu[cell];
  const float* br = ga.br[cell];
  const float* bc = ga.bc[cell];
  const size_t abase = (size_t)(R0 + lr) * HID;

  // ---- u,r GEMMs over K=256 = [conv | h] ----
  f32x4 au[4] = {}, ar[4] = {};
  {
    const short* WuH = ga.WuH[cell]; const short* WuL = ga.WuL[cell];
    const short* WrH = ga.WrH[cell]; const short* WrL = ga.WrL[cell];
    #pragma unroll
    for (int ks = 0; ks < 8; ++ks) {
      const short* Ah = (ks < 4) ? chi : hhi;
      const short* Al = (ks < 4) ? clo : hlo;
      const int kk = (ks & 3) * 32 + kb;
      bf16x8 ah = *(const bf16x8*)&Ah[abase + kk];
      bf16x8 al = *(const bf16x8*)&Al[abase + kk];
      #pragma unroll
      for (int c = 0; c < 4; ++c) {
        const size_t wo = (size_t)(ch * 64 + c * 16 + lr) * 256 + ks * 32 + kb;
        bf16x8 bh = *(const bf16x8*)&WuH[wo];
        bf16x8 bl = *(const bf16x8*)&WuL[wo];
        au[c] = __builtin_amdgcn_mfma_f32_16x16x32_bf16(ah, bh, au[c], 0, 0, 0);
        au[c] = __builtin_amdgcn_mfma_f32_16x16x32_bf16(ah, bl, au[c], 0, 0, 0);
        au[c] = __builtin_amdgcn_mfma_f32_16x16x32_bf16(al, bh, au[c], 0, 0, 0);
        bh = *(const bf16x8*)&WrH[wo];
        bl = *(const bf16x8*)&WrL[wo];
        ar[c] = __builtin_amdgcn_mfma_f32_16x16x32_bf16(ah, bh, ar[c], 0, 0, 0);
        ar[c] = __builtin_amdgcn_mfma_f32_16x16x32_bf16(ah, bl, ar[c], 0, 0, 0);
        ar[c] = __builtin_amdgcn_mfma_f32_16x16x32_bf16(al, bh, ar[c], 0, 0, 0);
      }
    }
  }
  // epilogue: u, r; stage rh = r*h into LDS (acc layout: row = lg*4+q, col = l&15)
  float uu[4][4], hh[4][4];
  #pragma unroll
  for (int c = 0; c < 4; ++c) {
    const int col = ch * 64 + c * 16 + lr;
    #pragma unroll
    for (int q = 0; q < 4; ++q) {
      const int row = R0 + lg * 4 + q;
      const int n = row & (N - 1);
      const float uv = sigmoidf_(au[c][q] + bu[n]);
      const float rv = sigmoidf_(ar[c][q] + br[n]);
      const float hv = hsrc[(size_t)row * HID + col];
      uu[c][q] = uv; hh[c][q] = hv;
      my[lg * 4 + q][col] = rv * hv;
    }
  }
  __syncthreads();

  // ---- c GEMM over K=256 = [conv | r*h] ----
  f32x4 acg[4] = {};
  {
    const short* WcH = ga.WcH[cell]; const short* WcL = ga.WcL[cell];
    #pragma unroll
    for (int ks = 0; ks < 8; ++ks) {
      bf16x8 ah, al;
      if (ks < 4) {
        ah = *(const bf16x8*)&chi[abase + ks * 32 + kb];
        al = *(const bf16x8*)&clo[abase + ks * 32 + kb];
      } else {
        const float* p = &my[lr][(ks - 4) * 32 + kb];
        f32x4 f0 = *(const f32x4*)p;
        f32x4 f1 = *(const f32x4*)(p + 4);
        #pragma unroll
        for (int e = 0; e < 4; ++e) { short hi, lo; split_bf16(f0[e], hi, lo); ah[e] = hi; al[e] = lo; }
        #pragma unroll
        for (int e = 0; e < 4; ++e) { short hi, lo; split_bf16(f1[e], hi, lo); ah[4 + e] = hi; al[4 + e] = lo; }
      }
      #pragma unroll
      for (int c = 0; c < 4; ++c) {
        const size_t wo = (size_t)(ch * 64 + c * 16 + lr) * 256 + ks * 32 + kb;
        bf16x8 bh = *(const bf16x8*)&WcH[wo];
        bf16x8 bl = *(const bf16x8*)&WcL[wo];
        acg[c] = __builtin_amdgcn_mfma_f32_16x16x32_bf16(ah, bh, acg[c], 0, 0, 0);
        acg[c] = __builtin_amdgcn_mfma_f32_16x16x32_bf16(ah, bl, acg[c], 0, 0, 0);
        acg[c] = __builtin_amdgcn_mfma_f32_16x16x32_bf16(al, bh, acg[c], 0, 0, 0);
      }
    }
  }
  // epilogue: c, h' = u*h + (1-u)*c ; write fp32 + bf16
  float hp[4][4];
  float* hout = ga.hout[cell];
  __hip_bfloat16* hbo = ga.hb[cell];
  #pragma unroll
  for (int c = 0; c < 4; ++c) {
    const int col = ch * 64 + c * 16 + lr;
    #pragma unroll
    for (int q = 0; q < 4; ++q) {
      const int row = R0 + lg * 4 + q;
      const int n = row & (N - 1);
      const float cv = tanhf_(acg[c][q] + bc[n]);
      const float o = uu[c][q] * hh[c][q] + (1.f - uu[c][q]) * cv;
      hp[c][q] = o;
      hout[(size_t)row * HID + col] = o;
      hbo[(size_t)row * HID + col] = __float2bfloat16(o);
    }
  }
  __syncthreads();                    // all c-GEMM LDS reads done before overwrite
  #pragma unroll
  for (int c = 0; c < 4; ++c) {
    const int col = ch * 64 + c * 16 + lr;
    #pragma unroll
    for (int q = 0; q < 4; ++q) my[lg * 4 + q][col] = hp[c][q];
  }
  __syncthreads();

  // ---- g GEMM: g = h' @ R, K=128 ----
  f32x4 ag[4] = {};
  {
    const short* RtH = ga.RtH[cell]; const short* RtL = ga.RtL[cell];
    #pragma unroll
    for (int ks = 0; ks < 4; ++ks) {
      bf16x8 ah, al;
      const float* p = &my[lr][ks * 32 + kb];
      f32x4 f0 = *(const f32x4*)p;
      f32x4 f1 = *(const f32x4*)(p + 4);
      #pragma unroll
      for (int e = 0; e < 4; ++e) { short hi, lo; split_bf16(f0[e], hi, lo); ah[e] = hi; al[e] = lo; }
      #pragma unroll
      for (int e = 0; e < 4; ++e) { short hi, lo; split_bf16(f1[e], hi, lo); ah[4 + e] = hi; al[4 + e] = lo; }
      #pragma unroll
      for (int c = 0; c < 4; ++c) {
        const size_t wo = (size_t)(ch * 64 + c * 16 + lr) * 128 + ks * 32 + kb;
        bf16x8 bh = *(const bf16x8*)&RtH[wo];
        bf16x8 bl = *(const bf16x8*)&RtL[wo];
        ag[c] = __builtin_amdgcn_mfma_f32_16x16x32_bf16(ah, bh, ag[c], 0, 0, 0);
        ag[c] = __builtin_amdgcn_mfma_f32_16x16x32_bf16(ah, bl, ag[c], 0, 0, 0);
        ag[c] = __builtin_amdgcn_mfma_f32_16x16x32_bf16(al, bh, ag[c], 0, 0, 0);
      }
    }
  }
  __hip_bfloat16* gbo = ga.gb[cell];
  #pragma unroll
  for (int c = 0; c < 4; ++c) {
    const int col = ch * 64 + c * 16 + lr;
    #pragma unroll
    for (int q = 0; q < 4; ++q) {
      const int row = R0 + lg * 4 + q;
      gbo[(size_t)row * HID + col] = __float2bfloat16(ag[c][q]);
    }
  }
}

// ------------- K4: logits[b,i,j,k] = g_k[b,i,:] . h_k[b,j,:]  (bf16 MFMA, NT) -------------
__global__ __launch_bounds__(256) void k_bilinear(
    const __hip_bfloat16* __restrict__ g0, const __hip_bfloat16* __restrict__ g1,
    const __hip_bfloat16* __restrict__ g2, const __hip_bfloat16* __restrict__ h0,
    const __hip_bfloat16* __restrict__ h1, const __hip_bfloat16* __restrict__ h2,
    float* __restrict__ out) {
  const int ti = blockIdx.x, tj = blockIdx.y, b = blockIdx.z;
  const int t = threadIdx.x;
  const int w = t >> 6, l = t & 63;
  const int wi = w >> 1, wj = w & 1;
  const int i_base = ti * 64 + wi * 32;
  const int j_base = tj * 64 + wj * 32;
  const __hip_bfloat16* gbs[3] = {g0, g1, g2};
  const __hip_bfloat16* hbs[3] = {h0, h1, h2};
  const int lr = l & 15;
  const int kb = (l >> 4) * 8;
  f32x4 acc[3][2][2] = {};
  for (int k0 = 0; k0 < HID; k0 += 32) {
    bf16x8 af[3][2], bfr[3][2];
    #pragma unroll
    for (int d = 0; d < 3; ++d) {
      #pragma unroll
      for (int m = 0; m < 2; ++m) {
        af[d][m]  = *(const bf16x8*)&gbs[d][(size_t)(b * N + i_base + m * 16 + lr) * HID + k0 + kb];
        bfr[d][m] = *(const bf16x8*)&hbs[d][(size_t)(b * N + j_base + m * 16 + lr) * HID + k0 + kb];
      }
    }
    #pragma unroll
    for (int d = 0; d < 3; ++d)
      #pragma unroll
      for (int mi = 0; mi < 2; ++mi)
        #pragma unroll
        for (int mj = 0; mj < 2; ++mj)
          acc[d][mi][mj] = __builtin_amdgcn_mfma_f32_16x16x32_bf16(
              af[d][mi], bfr[d][mj], acc[d][mi][mj], 0, 0, 0);
  }
  const int orow = (l >> 4) * 4;
  const int col  = l & 15;
  #pragma unroll
  for (int mi = 0; mi < 2; ++mi)
    #pragma unroll
    for (int mj = 0; mj < 2; ++mj)
      #pragma unroll
      for (int r = 0; r < 4; ++r) {
        const int row = i_base + mi * 16 + orow + r;
        const int cc  = j_base + mj * 16 + col;
        float* p = &out[(((size_t)(b * N + row)) * N + cc) * 3];
        p[0] = acc[0][mi][mj][r];
        p[1] = acc[1][mi][mj][r];
        p[2] = acc[2][mi][mj][r];
      }
}

extern "C" void kernel_launch(void* const* d_in, const int* in_sizes, int n_in,
                              void* d_out, int out_size, void* d_ws, size_t ws_size,
                              hipStream_t stream) {
  (void)in_sizes; (void)n_in; (void)out_size; (void)ws_size;
  const float* x    = (const float*)d_in[0];
  const float* a    = (const float*)d_in[1];
  const float* gk   = (const float*)d_in[5];
  const float* asel = (const float*)d_in[6];
  const float* anei = (const float*)d_in[7];
  const float* bias = (const float*)d_in[8];

  float* ws      = (float*)d_ws;
  float* hfeat   = ws;                                    // BN*HID
  float* sself   = hfeat + (size_t)BN * HID;              // BN*H
  float* sneigh  = sself + (size_t)BN * H;                // BN*H
  short* sp      = (short*)(sneigh + (size_t)BN * H);
  auto alloc_s = [&](size_t n) { short* p = sp; sp += n; return p; };

  short* conv_hi = alloc_s((size_t)BN * HID);
  short* conv_lo = alloc_s((size_t)BN * HID);
  short* h_hi[3]; short* h_lo[3];
  for (int c = 0; c < 3; ++c) { h_hi[c] = alloc_s((size_t)BN * HID); h_lo[c] = alloc_s((size_t)BN * HID); }
  __hip_bfloat16* hbb[3]; __hip_bfloat16* gbb[3];
  for (int c = 0; c < 3; ++c) {
    hbb[c] = (__hip_bfloat16*)alloc_s((size_t)BN * HID);
    gbb[c] = (__hip_bfloat16*)alloc_s((size_t)BN * HID);
  }

  float* out = (float*)d_out;

  PrepArgs pa;
  GruArgs ga;
  ga.chi = conv_hi; ga.clo = conv_lo;
  ga.h[0] = (const float*)d_in[2];
  ga.h[1] = (const float*)d_in[3];
  ga.h[2] = (const float*)d_in[4];
  for (int c = 0; c < 3; ++c) {
    const int base = 9 + c * 6;
    ga.hhi[c] = h_hi[c]; ga.hlo[c] = h_lo[c];
    ga.bu[c] = (const float*)d_in[base + 1];
    ga.br[c] = (const float*)d_in[base + 3];
    ga.bc[c] = (const float*)d_in[base + 5];
    // weight prep slots: 4 per cell (Wu, Wr, Wc, R)
    short* wu_h = alloc_s(256 * 128); short* wu_l = alloc_s(256 * 128);
    short* wr_h = alloc_s(256 * 128); short* wr_l = alloc_s(256 * 128);
    short* wc_h = alloc_s(256 * 128); short* wc_l = alloc_s(256 * 128);
    short* rt_h = alloc_s(128 * 128); short* rt_l = alloc_s(128 * 128);
    const int pb = c * 4;
    pa.src[pb + 0] = (const float*)d_in[base + 0]; pa.hi[pb + 0] = wu_h; pa.lo[pb + 0] = wu_l; pa.K[pb + 0] = 256;
    pa.src[pb + 1] = (const float*)d_in[base + 2]; pa.hi[pb + 1] = wr_h; pa.lo[pb + 1] = wr_l; pa.K[pb + 1] = 256;
    pa.src[pb + 2] = (const float*)d_in[base + 4]; pa.hi[pb + 2] = wc_h; pa.lo[pb + 2] = wc_l; pa.K[pb + 2] = 256;
    pa.src[pb + 3] = (const float*)d_in[27 + c];   pa.hi[pb + 3] = rt_h; pa.lo[pb + 3] = rt_l; pa.K[pb + 3] = 128;
    ga.WuH[c] = wu_h; ga.WuL[c] = wu_l;
    ga.WrH[c] = wr_h; ga.WrL[c] = wr_l;
    ga.WcH[c] = wc_h; ga.WcL[c] = wc_l;
    ga.RtH[c] = rt_h; ga.RtL[c] = rt_l;
    ga.hout[c] = out + LOG_SZ + (size_t)c * BN * HID;
    ga.hb[c] = hbb[c];
    ga.gb[c] = gbb[c];
  }

  k_prep_w<<<dim3(32, 12), 256, 0, stream>>>(pa);
  k_feat<<<BN, 128, 0, stream>>>(x, gk, asel, anei, hfeat, sself, sneigh,
                                 ga.h[0], ga.h[1], ga.h[2],
                                 h_hi[0], h_lo[0], h_hi[1], h_lo[1], h_hi[2], h_lo[2]);
  k_attn<<<BN / 4, 256, 0, stream>>>(a, hfeat, sself, sneigh, bias, conv_hi, conv_lo);
  k_gru<<<dim3(BN / 64, 3), 512, 0, stream>>>(ga);
  dim3 g2(N / 64, N / 64, B);
  k_bilinear<<<g2, 256, 0, stream>>>(gbb[0], gbb[1], gbb[2],
                                     hbb[0], hbb[1], hbb[2], out);
}